// Round 2
// baseline (377.541 us; speedup 1.0000x reference)
//
#include <hip/hip_runtime.h>
#include <hip/hip_fp16.h>

// fePAM: per-pixel gather attention. Shapes fixed by setup_inputs().
constexpr int B = 2, C = 64, H = 128, W = 256, N = H * W, K = 32;

typedef _Float16 hf2 __attribute__((ext_vector_type(2)));

// DPP helper (VALU-pipe cross-lane)
template <int CTRL>
__device__ __forceinline__ float dppf(float x) {
    int i = __builtin_bit_cast(int, x);
    int r = __builtin_amdgcn_update_dpp(i, i, CTRL, 0xF, 0xF, false);
    return __builtin_bit_cast(float, r);
}
// 0xB1 quad_perm xor1 | 0x4E quad_perm xor2 | 0x141 row_half_mirror (xor4)
// 0x128 row_ror:8 == xor8 within a 16-lane row

__device__ __forceinline__ unsigned sel4(const uint4& v, int g) {
    return g == 0 ? v.x : g == 1 ? v.y : g == 2 ? v.z : v.w;
}
__device__ __forceinline__ unsigned sel4(const ushort4& v, int g) {
    return g == 0 ? v.x : g == 1 ? v.y : g == 2 ? v.z : v.w;
}

// ---------------------------------------------------------------------------
// Prep: z=0/1/2 transpose+fp16 S,R,Q: [B][C][N] -> plane-split [B*2][N][32]
// (plane q = 2b + (c>>5); channels 32..63 land in plane 2b+1 at pos c-32).
// Gather granule becomes 64 B; each plane table = 2.1 MB -> L2-resident
// per XCD during the phase that touches it.
// z=3 (b==0 only): pack idx16[n][slot]=px*W+py, slot=(k&7)*4+(k>>3).
// grid = (N/64, B, 4), block = 256.
// ---------------------------------------------------------------------------
__global__ __launch_bounds__(256) void fepam_prep(
    const float* __restrict__ Q, const float* __restrict__ S,
    const float* __restrict__ R,
    const int* __restrict__ Px, const int* __restrict__ Py,
    __half* __restrict__ Qt, __half* __restrict__ St, __half* __restrict__ Rt,
    unsigned short* __restrict__ Idx) {
    const int n0 = blockIdx.x * 64;
    const int b  = blockIdx.y;
    const int z  = blockIdx.z;

    if (z == 3) {
        if (b) return;
#pragma unroll
        for (int t = 0; t < 8; ++t) {
            const int e  = threadIdx.x + 256 * t;   // 0..2047
            const int nl = e >> 5, k = e & 31;
            const int n  = n0 + nl;
            const int idx = Px[(size_t)n * K + k] * W + Py[(size_t)n * K + k];
            Idx[(size_t)n * K + (k & 7) * 4 + (k >> 3)] = (unsigned short)idx;
        }
        return;
    }

    __shared__ float tile[C][65];
    const float* src = (z == 0 ? S : (z == 1 ? R : Q)) + (size_t)b * C * N;
    __half2* d2 = (__half2*)(z == 0 ? St : (z == 1 ? Rt : Qt));
    {
        const int j = threadIdx.x & 63, c0 = threadIdx.x >> 6;
        const float* s = src + n0 + j;
#pragma unroll
        for (int r = 0; r < 16; ++r) {
            int c = c0 + r * 4;
            tile[c][j] = s[(size_t)c * N];  // coalesced 256B along n
        }
    }
    __syncthreads();
    {
        const int c2 = threadIdx.x & 31, j0 = threadIdx.x >> 5;
        const int plane = c2 >> 4, c2l = c2 & 15;  // c2l: __half2 pos in plane
#pragma unroll
        for (int r = 0; r < 8; ++r) {
            int j = j0 + 8 * r;
            d2[((size_t)(2 * b + plane) * N + (n0 + j)) * 16 + c2l] =
                __floats2half2_rn(tile[2 * c2][j], tile[2 * c2 + 1][j]);
        }
    }
}

// ---------------------------------------------------------------------------
// Scores: two phases over channel planes; per-phase gather table 2.1 MB/batch
// -> L2-resident per XCD. Partial dots s[8][4] held in registers across
// phases; softmax deferred to after the plane loop (indices kept in ivs[8]).
// grid = (N/32 * B), block = 256 (4 waves; 1 wave = 8 pixels). No LDS.
// Software-pipelined: iv/q loaded 2 pixels ahead, keys 1 pixel ahead.
// Writes packed (idx<<16 | fp16 attn) to AI[b][n][k_loc*4+g].
// ---------------------------------------------------------------------------
__global__ __launch_bounds__(256, 6) void fepam_scores(
    const __half* __restrict__ Qt, const unsigned short* __restrict__ Idx,
    const __half* __restrict__ St, unsigned* __restrict__ AI) {
    const int tid  = threadIdx.x;
    const int lane = tid & 63;
    const int wave = tid >> 6;        // 0..3
    const int bx   = blockIdx.x;
    const int b    = bx & 1;          // XCD batch-parity swizzle
    const int n0   = (bx >> 1) * 32 + wave * 8;

    const int c_oct = lane & 7;
    const int k_loc = lane >> 3;

    unsigned* AIb = AI + (size_t)b * N * K;

    auto ldi = [&](int p) {
        return *(const ushort4*)(Idx + (size_t)(n0 + p) * K + k_loc * 4);
    };

    float s[8][4];
#pragma unroll
    for (int p = 0; p < 8; ++p)
#pragma unroll
        for (int g = 0; g < 4; ++g) s[p][g] = 0.f;
    ushort4 ivs[8];

#pragma unroll
    for (int P = 0; P < 2; ++P) {
        const __half* Kp = St + (size_t)(2 * b + P) * N * 32;
        const __half* Qp = Qt + (size_t)(2 * b + P) * N * 32;

        auto ldq = [&](int p) {
            return *(const float2*)(Qp + (size_t)(n0 + p) * 32 + c_oct * 4);
        };
        auto ldk = [&](const ushort4& iv, int g) {
            return *(const float2*)(Kp + (size_t)sel4(iv, g) * 32 + c_oct * 4);
        };

        ushort4 iv_c = ldi(0), iv_n = ldi(1);
        float2  q_c  = ldq(0), q_n  = ldq(1);
        float2  k_c[4];
#pragma unroll
        for (int g = 0; g < 4; ++g) k_c[g] = ldk(iv_c, g);

#pragma unroll
        for (int p = 0; p < 8; ++p) {
            // prefetch: keys for p+1, iv/q for p+2
            float2 k_n[4];
            if (p < 7) {
#pragma unroll
                for (int g = 0; g < 4; ++g) k_n[g] = ldk(iv_n, g);
            }
            ushort4 iv_2;
            float2  q_2;
            if (p < 6) { iv_2 = ldi(p + 2); q_2 = ldq(p + 2); }

            if (P == 0) ivs[p] = iv_c;

            // ---- accumulate partial dots for pixel p (4 channels/lane)
            const hf2* q2 = (const hf2*)&q_c;
#pragma unroll
            for (int g = 0; g < 4; ++g) {
                const hf2* k2 = (const hf2*)&k_c[g];
                float acc = s[p][g];
#pragma unroll
                for (int u = 0; u < 2; ++u)
                    acc = __builtin_amdgcn_fdot2(k2[u], q2[u], acc, false);
                s[p][g] = acc;
            }

            // ---- shift pipeline
#pragma unroll
            for (int g = 0; g < 4; ++g) k_c[g] = k_n[g];
            iv_c = iv_n; q_c = q_n;
            iv_n = iv_2; q_n = q_2;
        }
    }

    // ---- softmax + packed (idx|fp16 attn) store per pixel (register-only)
#pragma unroll
    for (int p = 0; p < 8; ++p) {
        float t[4];
#pragma unroll
        for (int g = 0; g < 4; ++g) {  // reduce over c_oct: pure DPP
            float v = s[p][g];
            v += dppf<0xB1>(v);
            v += dppf<0x4E>(v);
            v += dppf<0x141>(v);
            t[g] = v;
        }
        float m = fmaxf(fmaxf(t[0], t[1]), fmaxf(t[2], t[3]));
        m = fmaxf(m, dppf<0x128>(m));
        m = fmaxf(m, __shfl_xor(m, 16));
        m = fmaxf(m, __shfl_xor(m, 32));
        float e0 = __expf(t[0] - m), e1 = __expf(t[1] - m);
        float e2 = __expf(t[2] - m), e3 = __expf(t[3] - m);
        float l = (e0 + e1) + (e2 + e3);
        l += dppf<0x128>(l);
        l += __shfl_xor(l, 16);
        l += __shfl_xor(l, 32);
        const float inv = 1.0f / l;

        if (c_oct == 0) {  // 8 lanes x 16B = contiguous 128B per pixel
            const ushort4 iv = ivs[p];
            uint4 wv;
            wv.x = ((unsigned)iv.x << 16) |
                   __half_as_ushort(__float2half_rn(e0 * inv));
            wv.y = ((unsigned)iv.y << 16) |
                   __half_as_ushort(__float2half_rn(e1 * inv));
            wv.z = ((unsigned)iv.z << 16) |
                   __half_as_ushort(__float2half_rn(e2 * inv));
            wv.w = ((unsigned)iv.w << 16) |
                   __half_as_ushort(__float2half_rn(e3 * inv));
            *(uint4*)(AIb + (size_t)(n0 + p) * K + k_loc * 4) = wv;
        }
    }
}

// ---------------------------------------------------------------------------
// Values: two phases over output-channel planes; per-phase gather table
// 2.1 MB/batch -> L2-resident. Reads packed (idx|attn) words per phase.
// grid = (N/32 * B), block = 256 (4 waves; 1 wave = 8 pixels). LDS 8.4 KB.
// ---------------------------------------------------------------------------
__global__ __launch_bounds__(256, 6) void fepam_values(
    const unsigned* __restrict__ AI, const __half* __restrict__ Rt,
    float* __restrict__ Out) {
    __shared__ __align__(16) float ot[32][66];  // 8.4 KB

    const int tid  = threadIdx.x;
    const int lane = tid & 63;
    const int wave = tid >> 6;        // 0..3
    const int bx   = blockIdx.x;
    const int b    = bx & 1;
    const int n0t  = (bx >> 1) * 32;
    const int n0   = n0t + wave * 8;

    const int c_oct = lane & 7;
    const int k_loc = lane >> 3;
    const bool hi8  = (lane & 8)  != 0;
    const bool hi16 = (lane & 16) != 0;
    const bool hi32 = (lane & 32) != 0;

    const unsigned* AIb = AI + (size_t)b * N * K;

    auto ldw = [&](int p) {
        return *(const uint4*)(AIb + (size_t)(n0 + p) * K + k_loc * 4);
    };

#pragma unroll
    for (int P = 0; P < 2; ++P) {
        const __half* Vp = Rt + (size_t)(2 * b + P) * N * 32;

        auto ldv = [&](const uint4& wv, int g) {
            return *(const float2*)(Vp + (size_t)(sel4(wv, g) >> 16) * 32 +
                                    c_oct * 4);
        };

        uint4  w_c = ldw(0), w_n = ldw(1);
        float2 v_c[4];
#pragma unroll
        for (int g = 0; g < 4; ++g) v_c[g] = ldv(w_c, g);

#pragma unroll
        for (int p = 0; p < 8; ++p) {
            float2 v_n[4];
            if (p < 7) {
#pragma unroll
                for (int g = 0; g < 4; ++g) v_n[g] = ldv(w_n, g);
            }
            uint4 w_2;
            if (p < 6) w_2 = ldw(p + 2);

            // ---- accumulate pixel p: 4 plane-channels per lane
            const float a[4] = {
                __half2float(__ushort_as_half((unsigned short)(w_c.x & 0xffffu))),
                __half2float(__ushort_as_half((unsigned short)(w_c.y & 0xffffu))),
                __half2float(__ushort_as_half((unsigned short)(w_c.z & 0xffffu))),
                __half2float(__ushort_as_half((unsigned short)(w_c.w & 0xffffu)))};
            float acc[4] = {0.f, 0.f, 0.f, 0.f};
#pragma unroll
            for (int g = 0; g < 4; ++g) {
                const __half2* v2 = (const __half2*)&v_c[g];
                const float2 f0 = __half22float2(v2[0]);
                const float2 f1 = __half22float2(v2[1]);
                acc[0] = fmaf(a[g], f0.x, acc[0]);
                acc[1] = fmaf(a[g], f0.y, acc[1]);
                acc[2] = fmaf(a[g], f1.x, acc[2]);
                acc[3] = fmaf(a[g], f1.y, acc[3]);
            }

            // reduce acc[4] over k_loc: xor8/xor16 with payload halving,
            // xor32 full-add (both halves end with the same channel).
            float r2[2];
#pragma unroll
            for (int i = 0; i < 2; ++i) {
                const float send = hi8 ? acc[i] : acc[2 + i];
                const float recv = dppf<0x128>(send);
                r2[i] = (hi8 ? acc[2 + i] : acc[i]) + recv;
            }
            float r1;
            {
                const float send = hi16 ? r2[0] : r2[1];
                const float recv = __shfl_xor(send, 16);
                r1 = (hi16 ? r2[1] : r2[0]) + recv;
            }
            r1 += __shfl_xor(r1, 32);
            if (!hi32) {
                const int c =
                    P * 32 + c_oct * 4 + (hi8 ? 2 : 0) + (hi16 ? 1 : 0);
                ot[wave * 8 + p][c] = r1;
            }

            // ---- shift pipeline
#pragma unroll
            for (int g = 0; g < 4; ++g) v_c[g] = v_n[g];
            w_c = w_n;
            w_n = w_2;
        }
    }
    __syncthreads();

    // store: ot[j][c] -> Out[b][c][n0t+j] (two 128B segments per instr)
    {
        const int j = tid & 31, c0 = tid >> 5;
        float* od = Out + (size_t)b * C * N + n0t + j;
#pragma unroll
        for (int r = 0; r < 8; ++r) {
            int c = c0 + r * 8;
            od[(size_t)c * N] = ot[j][c];
        }
    }
}

// ---------------------------------------------------------------------------
extern "C" void kernel_launch(void* const* d_in, const int* in_sizes, int n_in,
                              void* d_out, int out_size, void* d_ws, size_t ws_size,
                              hipStream_t stream) {
    const float* Q  = (const float*)d_in[0];
    const float* S  = (const float*)d_in[1];
    const float* R  = (const float*)d_in[2];
    const int*   Px = (const int*)d_in[3];
    const int*   Py = (const int*)d_in[4];
    float* Out = (float*)d_out;

    // ws: St, Rt, Qt (8.39 MB each, plane-split [B*2][N][32]) +
    //     Idx (2.1 MB) + AI packed (8.39 MB)
    __half* St = (__half*)d_ws;
    __half* Rt = St + (size_t)B * N * C;
    __half* Qt = Rt + (size_t)B * N * C;
    unsigned short* Idx = (unsigned short*)(Qt + (size_t)B * N * C);
    unsigned* AI = (unsigned*)(Idx + (size_t)N * K);

    dim3 pgrid(N / 64, B, 4);
    fepam_prep<<<pgrid, 256, 0, stream>>>(Q, S, R, Px, Py, Qt, St, Rt, Idx);

    dim3 ggrid(N / 32 * B);
    fepam_scores<<<ggrid, 256, 0, stream>>>(Qt, Idx, St, AI);
    fepam_values<<<ggrid, 256, 0, stream>>>(AI, Rt, Out);
}

// Round 3
// 160.805 us; speedup vs baseline: 2.3478x; 2.3478x over previous
//
#include <hip/hip_runtime.h>
#include <hip/hip_fp16.h>

// fePAM: per-pixel gather attention. Shapes fixed by setup_inputs().
constexpr int B = 2, C = 64, H = 128, W = 256, N = H * W, K = 32;

typedef _Float16 hf2 __attribute__((ext_vector_type(2)));

// DPP helper (VALU-pipe cross-lane)
template <int CTRL>
__device__ __forceinline__ float dppf(float x) {
    int i = __builtin_bit_cast(int, x);
    int r = __builtin_amdgcn_update_dpp(i, i, CTRL, 0xF, 0xF, false);
    return __builtin_bit_cast(float, r);
}
// 0xB1 quad_perm xor1 | 0x4E quad_perm xor2 | 0x141 row_half_mirror (xor4)
// 0x128 row_ror:8 == xor8 within a 16-lane row

__device__ __forceinline__ unsigned sel4(const ushort4& v, int g) {
    return g == 0 ? v.x : g == 1 ? v.y : g == 2 ? v.z : v.w;
}

// ---------------------------------------------------------------------------
// Prep: z=0/1/2 transpose+fp16 S,R,Q: [B][C][N] -> plane-split [B*2][N][32]
// (plane q = 2b + (c>>5)). Gather granule 64 B; each plane table = 2.1 MB.
// z=3 (b==0 only): pack idx16[n][slot]=px*W+py, slot=(k&7)*4+(k>>3).
// grid = (N/64, B, 4), block = 256.   [verified in round 2]
// ---------------------------------------------------------------------------
__global__ __launch_bounds__(256) void fepam_prep(
    const float* __restrict__ Q, const float* __restrict__ S,
    const float* __restrict__ R,
    const int* __restrict__ Px, const int* __restrict__ Py,
    __half* __restrict__ Qt, __half* __restrict__ St, __half* __restrict__ Rt,
    unsigned short* __restrict__ Idx) {
    const int n0 = blockIdx.x * 64;
    const int b  = blockIdx.y;
    const int z  = blockIdx.z;

    if (z == 3) {
        if (b) return;
#pragma unroll
        for (int t = 0; t < 8; ++t) {
            const int e  = threadIdx.x + 256 * t;   // 0..2047
            const int nl = e >> 5, k = e & 31;
            const int n  = n0 + nl;
            const int idx = Px[(size_t)n * K + k] * W + Py[(size_t)n * K + k];
            Idx[(size_t)n * K + (k & 7) * 4 + (k >> 3)] = (unsigned short)idx;
        }
        return;
    }

    __shared__ float tile[C][65];
    const float* src = (z == 0 ? S : (z == 1 ? R : Q)) + (size_t)b * C * N;
    __half2* d2 = (__half2*)(z == 0 ? St : (z == 1 ? Rt : Qt));
    {
        const int j = threadIdx.x & 63, c0 = threadIdx.x >> 6;
        const float* s = src + n0 + j;
#pragma unroll
        for (int r = 0; r < 16; ++r) {
            int c = c0 + r * 4;
            tile[c][j] = s[(size_t)c * N];  // coalesced 256B along n
        }
    }
    __syncthreads();
    {
        const int c2 = threadIdx.x & 31, j0 = threadIdx.x >> 5;
        const int plane = c2 >> 4, c2l = c2 & 15;  // c2l: __half2 pos in plane
#pragma unroll
        for (int r = 0; r < 8; ++r) {
            int j = j0 + 8 * r;
            d2[((size_t)(2 * b + plane) * N + (n0 + j)) * 16 + c2l] =
                __floats2half2_rn(tile[2 * c2][j], tile[2 * c2 + 1][j]);
        }
    }
}

// ---------------------------------------------------------------------------
// Scores (partial): each block owns ONE (batch, plane) combo, selected by
// bx&3 so each XCD (bx%8 round-robin) only ever gathers from a single
// 2.1 MB key table -> truly L2-resident. Computes half-dot t[g] over the
// plane's 32 channels and writes fp16 partials Sp[2b+P][n][slot].
// grid = (N/32)*B*2, block = 256 (4 waves; 1 wave = 8 pixels). No LDS.
// ---------------------------------------------------------------------------
__global__ __launch_bounds__(256, 6) void fepam_scores(
    const __half* __restrict__ Qt, const unsigned short* __restrict__ Idx,
    const __half* __restrict__ St, __half* __restrict__ Sp) {
    const int tid  = threadIdx.x;
    const int lane = tid & 63;
    const int wave = tid >> 6;        // 0..3
    const int bx   = blockIdx.x;
    const int b    = bx & 1;          // XCD-pinned batch
    const int P    = (bx >> 1) & 1;   // XCD-pinned plane
    const int n0   = (bx >> 2) * 32 + wave * 8;

    const int c_oct = lane & 7;
    const int k_loc = lane >> 3;

    const __half* Kp = St + (size_t)(2 * b + P) * N * 32;
    const __half* Qp = Qt + (size_t)(2 * b + P) * N * 32;
    __half* Spq = Sp + (size_t)(2 * b + P) * N * K;

    auto ldi = [&](int p) {
        return *(const ushort4*)(Idx + (size_t)(n0 + p) * K + k_loc * 4);
    };
    auto ldq = [&](int p) {
        return *(const float2*)(Qp + (size_t)(n0 + p) * 32 + c_oct * 4);
    };
    auto ldk = [&](const ushort4& iv, int g) {
        return *(const float2*)(Kp + (size_t)sel4(iv, g) * 32 + c_oct * 4);
    };

    ushort4 iv_c = ldi(0), iv_n = ldi(1);
    float2  q_c  = ldq(0), q_n  = ldq(1);
    float2  k_c[4];
#pragma unroll
    for (int g = 0; g < 4; ++g) k_c[g] = ldk(iv_c, g);

#pragma unroll
    for (int p = 0; p < 8; ++p) {
        // prefetch: keys for p+1, iv/q for p+2
        float2 k_n[4];
        if (p < 7) {
#pragma unroll
            for (int g = 0; g < 4; ++g) k_n[g] = ldk(iv_n, g);
        }
        ushort4 iv_2;
        float2  q_2;
        if (p < 6) { iv_2 = ldi(p + 2); q_2 = ldq(p + 2); }

        // ---- partial dot for pixel p (4 plane-channels per lane)
        float t[4];
        const hf2* q2 = (const hf2*)&q_c;
#pragma unroll
        for (int g = 0; g < 4; ++g) {
            const hf2* k2 = (const hf2*)&k_c[g];
            float acc = 0.f;
#pragma unroll
            for (int u = 0; u < 2; ++u)
                acc = __builtin_amdgcn_fdot2(k2[u], q2[u], acc, false);
            // reduce over c_oct: pure DPP (xor1, xor2, xor4)
            acc += dppf<0xB1>(acc);
            acc += dppf<0x4E>(acc);
            acc += dppf<0x141>(acc);
            t[g] = acc;
        }

        if (c_oct == 0) {  // 8 lanes x 8B = contiguous 64B per pixel
            ushort4 hv;
            hv.x = __half_as_ushort(__float2half_rn(t[0]));
            hv.y = __half_as_ushort(__float2half_rn(t[1]));
            hv.z = __half_as_ushort(__float2half_rn(t[2]));
            hv.w = __half_as_ushort(__float2half_rn(t[3]));
            *(ushort4*)(Spq + (size_t)(n0 + p) * K + k_loc * 4) = hv;
        }

        // ---- shift pipeline
#pragma unroll
        for (int g = 0; g < 4; ++g) k_c[g] = k_n[g];
        iv_c = iv_n; q_c = q_n;
        iv_n = iv_2; q_n = q_2;
    }
}

// ---------------------------------------------------------------------------
// Values (+fused softmax): each block owns ONE (batch, plane) combo (bx&3,
// XCD-pinned like scores) -> gathers only its 2.1 MB value table. Per pixel:
// read both fp16 partials + Idx (streaming), redo softmax in-register
// (redundant across c_oct, cheap), gather V, FMA, reduce, write 32 output
// channels. grid = (N/32)*B*2, block = 256. LDS 4.2 KB.
// ---------------------------------------------------------------------------
__global__ __launch_bounds__(256, 6) void fepam_values(
    const unsigned short* __restrict__ Idx, const __half* __restrict__ Sp,
    const __half* __restrict__ Rt, float* __restrict__ Out) {
    __shared__ __align__(16) float ot[32][33];  // 4.2 KB

    const int tid  = threadIdx.x;
    const int lane = tid & 63;
    const int wave = tid >> 6;        // 0..3
    const int bx   = blockIdx.x;
    const int b    = bx & 1;
    const int P    = (bx >> 1) & 1;
    const int n0t  = (bx >> 2) * 32;
    const int n0   = n0t + wave * 8;

    const int c_oct = lane & 7;
    const int k_loc = lane >> 3;
    const bool hi8  = (lane & 8)  != 0;
    const bool hi16 = (lane & 16) != 0;
    const bool hi32 = (lane & 32) != 0;

    const __half* Vp  = Rt + (size_t)(2 * b + P) * N * 32;
    const __half* Sp0 = Sp + (size_t)(2 * b + 0) * N * K;
    const __half* Sp1 = Sp + (size_t)(2 * b + 1) * N * K;

    auto ldi = [&](int p) {
        return *(const ushort4*)(Idx + (size_t)(n0 + p) * K + k_loc * 4);
    };
    auto lds0 = [&](int p) {
        return *(const ushort4*)(Sp0 + (size_t)(n0 + p) * K + k_loc * 4);
    };
    auto lds1 = [&](int p) {
        return *(const ushort4*)(Sp1 + (size_t)(n0 + p) * K + k_loc * 4);
    };
    auto ldv = [&](const ushort4& iv, int g) {
        return *(const float2*)(Vp + (size_t)sel4(iv, g) * 32 + c_oct * 4);
    };

    ushort4 i_c = ldi(0), i_n = ldi(1);
    ushort4 a0_c = lds0(0), a0_n = lds0(1);
    ushort4 a1_c = lds1(0), a1_n = lds1(1);
    float2 v_c[4];
#pragma unroll
    for (int g = 0; g < 4; ++g) v_c[g] = ldv(i_c, g);

#pragma unroll
    for (int p = 0; p < 8; ++p) {
        float2 v_n[4];
        if (p < 7) {
#pragma unroll
            for (int g = 0; g < 4; ++g) v_n[g] = ldv(i_n, g);
        }
        ushort4 i_2, a0_2, a1_2;
        if (p < 6) { i_2 = ldi(p + 2); a0_2 = lds0(p + 2); a1_2 = lds1(p + 2); }

        // ---- softmax for pixel p (all lanes; c_oct copies redundant)
        float s[4];
#pragma unroll
        for (int g = 0; g < 4; ++g)
            s[g] = __half2float(__ushort_as_half(sel4(a0_c, g))) +
                   __half2float(__ushort_as_half(sel4(a1_c, g)));
        float m = fmaxf(fmaxf(s[0], s[1]), fmaxf(s[2], s[3]));
        m = fmaxf(m, dppf<0x128>(m));
        m = fmaxf(m, __shfl_xor(m, 16));
        m = fmaxf(m, __shfl_xor(m, 32));
        float e0 = __expf(s[0] - m), e1 = __expf(s[1] - m);
        float e2 = __expf(s[2] - m), e3 = __expf(s[3] - m);
        float l = (e0 + e1) + (e2 + e3);
        l += dppf<0x128>(l);
        l += __shfl_xor(l, 16);
        l += __shfl_xor(l, 32);
        const float inv = 1.0f / l;
        const float a[4] = {e0 * inv, e1 * inv, e2 * inv, e3 * inv};

        // ---- accumulate pixel p: 4 plane-channels per lane
        float acc[4] = {0.f, 0.f, 0.f, 0.f};
#pragma unroll
        for (int g = 0; g < 4; ++g) {
            const __half2* v2 = (const __half2*)&v_c[g];
            const float2 f0 = __half22float2(v2[0]);
            const float2 f1 = __half22float2(v2[1]);
            acc[0] = fmaf(a[g], f0.x, acc[0]);
            acc[1] = fmaf(a[g], f0.y, acc[1]);
            acc[2] = fmaf(a[g], f1.x, acc[2]);
            acc[3] = fmaf(a[g], f1.y, acc[3]);
        }

        // reduce acc[4] over k_loc: xor8/xor16 payload halving, xor32 full.
        float r2[2];
#pragma unroll
        for (int i = 0; i < 2; ++i) {
            const float send = hi8 ? acc[i] : acc[2 + i];
            const float recv = dppf<0x128>(send);
            r2[i] = (hi8 ? acc[2 + i] : acc[i]) + recv;
        }
        float r1;
        {
            const float send = hi16 ? r2[0] : r2[1];
            const float recv = __shfl_xor(send, 16);
            r1 = (hi16 ? r2[1] : r2[0]) + recv;
        }
        r1 += __shfl_xor(r1, 32);
        if (!hi32) {
            const int c = c_oct * 4 + (hi8 ? 2 : 0) + (hi16 ? 1 : 0);
            ot[wave * 8 + p][c] = r1;
        }

        // ---- shift pipeline
#pragma unroll
        for (int g = 0; g < 4; ++g) v_c[g] = v_n[g];
        i_c = i_n; a0_c = a0_n; a1_c = a1_n;
        i_n = i_2; a0_n = a0_2; a1_n = a1_2;
    }
    __syncthreads();

    // store: ot[j][c] -> Out[b][P*32+c][n0t+j] (128B segments per c-row)
    {
        const int j = tid & 31, c0 = tid >> 5;
        float* od = Out + (size_t)b * C * N + (size_t)P * 32 * N + n0t + j;
#pragma unroll
        for (int r = 0; r < 4; ++r) {
            int c = c0 + r * 8;
            od[(size_t)c * N] = ot[j][c];
        }
    }
}

// ---------------------------------------------------------------------------
extern "C" void kernel_launch(void* const* d_in, const int* in_sizes, int n_in,
                              void* d_out, int out_size, void* d_ws, size_t ws_size,
                              hipStream_t stream) {
    const float* Q  = (const float*)d_in[0];
    const float* S  = (const float*)d_in[1];
    const float* R  = (const float*)d_in[2];
    const int*   Px = (const int*)d_in[3];
    const int*   Py = (const int*)d_in[4];
    float* Out = (float*)d_out;

    // ws: St, Rt, Qt (8.39 MB each, plane-split [B*2][N][32]) +
    //     Idx (2.1 MB) + Sp fp16 partial scores [B*2][N][K] (8.39 MB)
    __half* St = (__half*)d_ws;
    __half* Rt = St + (size_t)B * N * C;
    __half* Qt = Rt + (size_t)B * N * C;
    unsigned short* Idx = (unsigned short*)(Qt + (size_t)B * N * C);
    __half* Sp = (__half*)(Idx + (size_t)N * K);

    dim3 pgrid(N / 64, B, 4);
    fepam_prep<<<pgrid, 256, 0, stream>>>(Q, S, R, Px, Py, Qt, St, Rt, Idx);

    dim3 ggrid(N / 32 * B * 2);
    fepam_scores<<<ggrid, 256, 0, stream>>>(Qt, Idx, St, Sp);
    fepam_values<<<ggrid, 256, 0, stream>>>(Idx, Sp, Rt, Out);
}

// Round 5
// 157.538 us; speedup vs baseline: 2.3965x; 1.0207x over previous
//
#include <hip/hip_runtime.h>
#include <hip/hip_fp16.h>

// fePAM: per-pixel gather attention. Shapes fixed by setup_inputs().
// Structure: verified R0 baseline (136 us) + occupancy 8/CU + NT stream hints.
constexpr int B = 2, C = 64, H = 128, W = 256, N = H * W, K = 32;

typedef _Float16 hf2 __attribute__((ext_vector_type(2)));
// ext-vector types: required by __builtin_nontemporal_* (HIP_vector_type is a
// class and is rejected); same layout as float4/uint4/ushort4.
typedef float f32x4 __attribute__((ext_vector_type(4)));
typedef unsigned u32x4 __attribute__((ext_vector_type(4)));
typedef unsigned short u16x4 __attribute__((ext_vector_type(4)));

// DPP helper (VALU-pipe cross-lane)
template <int CTRL>
__device__ __forceinline__ float dppf(float x) {
    int i = __builtin_bit_cast(int, x);
    int r = __builtin_amdgcn_update_dpp(i, i, CTRL, 0xF, 0xF, false);
    return __builtin_bit_cast(float, r);
}
// 0xB1 quad_perm xor1 | 0x4E quad_perm xor2 | 0x141 row_half_mirror (xor4)
// 0x128 row_ror:8 == xor8 within a 16-lane row

__device__ __forceinline__ unsigned sel4(const u32x4& v, int g) {
    return g == 0 ? v.x : g == 1 ? v.y : g == 2 ? v.z : v.w;
}
__device__ __forceinline__ unsigned sel4(const u16x4& v, int g) {
    return g == 0 ? v.x : g == 1 ? v.y : g == 2 ? v.z : v.w;
}

// ---------------------------------------------------------------------------
// Prep: z=0/1/2 transpose+fp16 S,R,Q: [B][C][N] -> [B][N][C].
// z=3 (b==0 only): pack idx16[n][slot]=px*W+py, slot=(k&7)*4+(k>>3).
// grid = (N/64, B, 4), block = 256. Stream reads NT (don't pollute L2).
// ---------------------------------------------------------------------------
__global__ __launch_bounds__(256) void fepam_prep(
    const float* __restrict__ Q, const float* __restrict__ S,
    const float* __restrict__ R,
    const int* __restrict__ Px, const int* __restrict__ Py,
    __half* __restrict__ Qt, __half* __restrict__ St, __half* __restrict__ Rt,
    unsigned short* __restrict__ Idx) {
    const int n0 = blockIdx.x * 64;
    const int b  = blockIdx.y;
    const int z  = blockIdx.z;

    if (z == 3) {
        if (b) return;
#pragma unroll
        for (int t = 0; t < 8; ++t) {
            const int e  = threadIdx.x + 256 * t;   // 0..2047
            const int nl = e >> 5, k = e & 31;
            const int n  = n0 + nl;
            const int ix = __builtin_nontemporal_load(Px + (size_t)n * K + k);
            const int iy = __builtin_nontemporal_load(Py + (size_t)n * K + k);
            Idx[(size_t)n * K + (k & 7) * 4 + (k >> 3)] =
                (unsigned short)(ix * W + iy);
        }
        return;
    }

    __shared__ float tile[C][65];
    const float* src = (z == 0 ? S : (z == 1 ? R : Q)) + (size_t)b * C * N;
    __half2* d2 = (__half2*)((z == 0 ? St : (z == 1 ? Rt : Qt)) +
                             (size_t)b * N * C);
    {
        const int j = threadIdx.x & 63, c0 = threadIdx.x >> 6;
        const float* s = src + n0 + j;
#pragma unroll
        for (int r = 0; r < 16; ++r) {
            int c = c0 + r * 4;
            tile[c][j] = __builtin_nontemporal_load(s + (size_t)c * N);
        }
    }
    __syncthreads();
    {
        const int c2 = threadIdx.x & 31, j0 = threadIdx.x >> 5;
#pragma unroll
        for (int r = 0; r < 8; ++r) {
            int j = j0 + 8 * r;
            d2[(size_t)(n0 + j) * 32 + c2] =
                __floats2half2_rn(tile[2 * c2][j], tile[2 * c2 + 1][j]);
        }
    }
}

// ---------------------------------------------------------------------------
// Scores: touches ONLY St as gather table (4.19 MB/batch, batch-pinned per
// XCD via bx&1). Streams (Qt, Idx, AI) are NT so they don't evict the table.
// grid = (N/32 * B) = 2048 = exactly 8 blocks/CU, block = 256 (4 waves;
// 1 wave = 8 pixels). No LDS. Software-pipelined: iv/q 2 ahead, keys 1 ahead.
// Writes packed (idx<<16 | fp16 attn) to AI[b][n][k_loc*4+g].
// ---------------------------------------------------------------------------
__global__ __launch_bounds__(256, 8) void fepam_scores(
    const __half* __restrict__ Qt, const unsigned short* __restrict__ Idx,
    const __half* __restrict__ St, unsigned* __restrict__ AI) {
    const int tid  = threadIdx.x;
    const int lane = tid & 63;
    const int wave = tid >> 6;        // 0..3
    const int bx   = blockIdx.x;
    const int b    = bx & 1;          // XCD batch-parity swizzle
    const int n0   = (bx >> 1) * 32 + wave * 8;

    const int c_oct = lane & 7;
    const int k_loc = lane >> 3;

    const __half* Qtb = Qt + (size_t)b * N * C;
    const __half* Stb = St + (size_t)b * N * C;
    unsigned* AIb = AI + (size_t)b * N * K;

    auto ldi = [&](int p) {
        return __builtin_nontemporal_load(
            (const u16x4*)(Idx + (size_t)(n0 + p) * K + k_loc * 4));
    };
    auto ldq = [&](int p) {
        return __builtin_nontemporal_load(
            (const f32x4*)(Qtb + (size_t)(n0 + p) * C + c_oct * 8));
    };
    auto ldk = [&](const u16x4& iv, int g) {
        return *(const f32x4*)(Stb + ((size_t)sel4(iv, g) << 6) + c_oct * 8);
    };

    u16x4 iv_c = ldi(0), iv_n = ldi(1);
    f32x4 q_c  = ldq(0), q_n  = ldq(1);
    f32x4 k_c[4];
#pragma unroll
    for (int g = 0; g < 4; ++g) k_c[g] = ldk(iv_c, g);

#pragma unroll
    for (int p = 0; p < 8; ++p) {
        // prefetch: keys for p+1, iv/q for p+2
        f32x4 k_n[4];
        if (p < 7) {
#pragma unroll
            for (int g = 0; g < 4; ++g) k_n[g] = ldk(iv_n, g);
        }
        u16x4 iv_2;
        f32x4 q_2;
        if (p < 6) { iv_2 = ldi(p + 2); q_2 = ldq(p + 2); }

        // ---- compute pixel p
        float s[4];
#pragma unroll
        for (int g = 0; g < 4; ++g) {
            const hf2* k2 = (const hf2*)&k_c[g];
            const hf2* q2 = (const hf2*)&q_c;
            float acc = 0.f;
#pragma unroll
            for (int u = 0; u < 4; ++u)
                acc = __builtin_amdgcn_fdot2(k2[u], q2[u], acc, false);
            s[g] = acc;
        }
#pragma unroll
        for (int g = 0; g < 4; ++g) {  // reduce over c_oct: pure DPP
            s[g] += dppf<0xB1>(s[g]);
            s[g] += dppf<0x4E>(s[g]);
            s[g] += dppf<0x141>(s[g]);
        }
        float m = fmaxf(fmaxf(s[0], s[1]), fmaxf(s[2], s[3]));
        m = fmaxf(m, dppf<0x128>(m));
        m = fmaxf(m, __shfl_xor(m, 16));
        m = fmaxf(m, __shfl_xor(m, 32));
        float e0 = __expf(s[0] - m), e1 = __expf(s[1] - m);
        float e2 = __expf(s[2] - m), e3 = __expf(s[3] - m);
        float l = (e0 + e1) + (e2 + e3);
        l += dppf<0x128>(l);
        l += __shfl_xor(l, 16);
        l += __shfl_xor(l, 32);
        const float inv = 1.0f / l;

        if (c_oct == 0) {  // 8 lanes x 16B = contiguous 128B per pixel
            u32x4 wv;
            wv.x = ((unsigned)iv_c.x << 16) |
                   __half_as_ushort(__float2half_rn(e0 * inv));
            wv.y = ((unsigned)iv_c.y << 16) |
                   __half_as_ushort(__float2half_rn(e1 * inv));
            wv.z = ((unsigned)iv_c.z << 16) |
                   __half_as_ushort(__float2half_rn(e2 * inv));
            wv.w = ((unsigned)iv_c.w << 16) |
                   __half_as_ushort(__float2half_rn(e3 * inv));
            __builtin_nontemporal_store(
                wv, (u32x4*)(AIb + (size_t)(n0 + p) * K + k_loc * 4));
        }

        // ---- shift pipeline
#pragma unroll
        for (int g = 0; g < 4; ++g) k_c[g] = k_n[g];
        iv_c = iv_n; q_c = q_n;
        iv_n = iv_2; q_n = q_2;
    }
}

// ---------------------------------------------------------------------------
// Values: touches ONLY Rt as gather table (4.19 MB/batch, batch-pinned).
// Streams (AI read, Out write) NT. grid = 2048 = 8 blocks/CU, block = 256.
// LDS 8.4 KB (x8 = 67 KB/CU, fits). Software-pipelined like fepam_scores.
// ---------------------------------------------------------------------------
__global__ __launch_bounds__(256, 8) void fepam_values(
    const unsigned* __restrict__ AI, const __half* __restrict__ Rt,
    float* __restrict__ Out) {
    __shared__ __align__(16) float ot[32][66];  // 8.4 KB

    const int tid  = threadIdx.x;
    const int lane = tid & 63;
    const int wave = tid >> 6;        // 0..3
    const int bx   = blockIdx.x;
    const int b    = bx & 1;
    const int n0t  = (bx >> 1) * 32;
    const int n0   = n0t + wave * 8;

    const int c_oct = lane & 7;
    const int k_loc = lane >> 3;
    const bool hi8  = (lane & 8)  != 0;
    const bool hi16 = (lane & 16) != 0;
    const bool hi32 = (lane & 32) != 0;

    const __half* Rtb = Rt + (size_t)b * N * C;
    const unsigned* AIb = AI + (size_t)b * N * K;

    auto ldw = [&](int p) {
        return __builtin_nontemporal_load(
            (const u32x4*)(AIb + (size_t)(n0 + p) * K + k_loc * 4));
    };
    auto ldv = [&](const u32x4& wv, int g) {
        return *(const f32x4*)(Rtb + ((size_t)(sel4(wv, g) >> 16) << 6) +
                               c_oct * 8);
    };

    u32x4 w_c = ldw(0), w_n = ldw(1);
    f32x4 v_c[4];
#pragma unroll
    for (int g = 0; g < 4; ++g) v_c[g] = ldv(w_c, g);

#pragma unroll
    for (int p = 0; p < 8; ++p) {
        f32x4 v_n[4];
        if (p < 7) {
#pragma unroll
            for (int g = 0; g < 4; ++g) v_n[g] = ldv(w_n, g);
        }
        u32x4 w_2;
        if (p < 6) w_2 = ldw(p + 2);

        // ---- compute pixel p
        const float a[4] = {
            __half2float(__ushort_as_half((unsigned short)(w_c.x & 0xffffu))),
            __half2float(__ushort_as_half((unsigned short)(w_c.y & 0xffffu))),
            __half2float(__ushort_as_half((unsigned short)(w_c.z & 0xffffu))),
            __half2float(__ushort_as_half((unsigned short)(w_c.w & 0xffffu)))};
        float acc[8] = {0, 0, 0, 0, 0, 0, 0, 0};
#pragma unroll
        for (int g = 0; g < 4; ++g) {
            const __half2* v2 = (const __half2*)&v_c[g];
#pragma unroll
            for (int u = 0; u < 4; ++u) {
                const float2 vf = __half22float2(v2[u]);
                acc[2 * u]     = fmaf(a[g], vf.x, acc[2 * u]);
                acc[2 * u + 1] = fmaf(a[g], vf.y, acc[2 * u + 1]);
            }
        }

        // reduce acc[8] over k_loc (xor 8,16,32) with payload halving
        float r4[4];
#pragma unroll
        for (int i = 0; i < 4; ++i) {
            const float send = hi8 ? acc[i] : acc[4 + i];
            const float recv = dppf<0x128>(send);
            r4[i] = (hi8 ? acc[4 + i] : acc[i]) + recv;
        }
        float r2[2];
#pragma unroll
        for (int i = 0; i < 2; ++i) {
            const float send = hi16 ? r4[i] : r4[2 + i];
            const float recv = __shfl_xor(send, 16);
            r2[i] = (hi16 ? r4[2 + i] : r4[i]) + recv;
        }
        {
            const float send = hi32 ? r2[0] : r2[1];
            const float recv = __shfl_xor(send, 32);
            const float r1   = (hi32 ? r2[1] : r2[0]) + recv;
            const int c = c_oct * 8 + (hi8 ? 4 : 0) + (hi16 ? 2 : 0) + (hi32 ? 1 : 0);
            ot[wave * 8 + p][c] = r1;
        }

        // ---- shift pipeline
#pragma unroll
        for (int g = 0; g < 4; ++g) v_c[g] = v_n[g];
        w_c = w_n;
        w_n = w_2;
    }
    __syncthreads();

    // store: ot[j][c] -> Out[b][c][n0t+j] (two 128B segments per instr)
    {
        const int j = tid & 31, c0 = tid >> 5;
        float* od = Out + (size_t)b * C * N + n0t + j;
#pragma unroll
        for (int r = 0; r < 8; ++r) {
            int c = c0 + r * 8;
            __builtin_nontemporal_store(ot[j][c], od + (size_t)c * N);
        }
    }
}

// ---------------------------------------------------------------------------
extern "C" void kernel_launch(void* const* d_in, const int* in_sizes, int n_in,
                              void* d_out, int out_size, void* d_ws, size_t ws_size,
                              hipStream_t stream) {
    const float* Q  = (const float*)d_in[0];
    const float* S  = (const float*)d_in[1];
    const float* R  = (const float*)d_in[2];
    const int*   Px = (const int*)d_in[3];
    const int*   Py = (const int*)d_in[4];
    float* Out = (float*)d_out;

    // ws: St, Rt, Qt (8.39 MB each) + Idx (2.1 MB) + AI packed (8.39 MB)
    __half* St = (__half*)d_ws;
    __half* Rt = St + (size_t)B * N * C;
    __half* Qt = Rt + (size_t)B * N * C;
    unsigned short* Idx = (unsigned short*)(Qt + (size_t)B * N * C);
    unsigned* AI = (unsigned*)(Idx + (size_t)N * K);

    dim3 pgrid(N / 64, B, 4);
    fepam_prep<<<pgrid, 256, 0, stream>>>(Q, S, R, Px, Py, Qt, St, Rt, Idx);

    dim3 ggrid(N / 32 * B);
    fepam_scores<<<ggrid, 256, 0, stream>>>(Qt, Idx, St, AI);
    fepam_values<<<ggrid, 256, 0, stream>>>(AI, Rt, Out);
}

// Round 7
// 142.676 us; speedup vs baseline: 2.6461x; 1.1042x over previous
//
#include <hip/hip_runtime.h>
#include <hip/hip_fp16.h>

// fePAM: per-pixel gather attention. Shapes fixed by setup_inputs().
// Structure: R0 baseline (136 us) with scores+values FUSED (weights staged in
// wave-private LDS; AI intermediate and one launch eliminated).
constexpr int B = 2, C = 64, H = 128, W = 256, N = H * W, K = 32;

typedef _Float16 hf2 __attribute__((ext_vector_type(2)));

// DPP helper (VALU-pipe cross-lane)
template <int CTRL>
__device__ __forceinline__ float dppf(float x) {
    int i = __builtin_bit_cast(int, x);
    int r = __builtin_amdgcn_update_dpp(i, i, CTRL, 0xF, 0xF, false);
    return __builtin_bit_cast(float, r);
}
// 0xB1 quad_perm xor1 | 0x4E quad_perm xor2 | 0x141 row_half_mirror (xor4)
// 0x128 row_ror:8 == xor8 within a 16-lane row

__device__ __forceinline__ unsigned sel4(const ushort4& v, int g) {
    return g == 0 ? v.x : g == 1 ? v.y : g == 2 ? v.z : v.w;
}

// ---------------------------------------------------------------------------
// Prep: z=0/1/2 transpose+fp16 S,R,Q: [B][C][N] -> [B][N][C].
// z=3 (b==0 only): pack idx16[n][slot]=px*W+py, slot=(k&7)*4+(k>>3).
// grid = (N/64, B, 4), block = 256.   [verbatim R0]
// ---------------------------------------------------------------------------
__global__ __launch_bounds__(256) void fepam_prep(
    const float* __restrict__ Q, const float* __restrict__ S,
    const float* __restrict__ R,
    const int* __restrict__ Px, const int* __restrict__ Py,
    __half* __restrict__ Qt, __half* __restrict__ St, __half* __restrict__ Rt,
    unsigned short* __restrict__ Idx) {
    const int n0 = blockIdx.x * 64;
    const int b  = blockIdx.y;
    const int z  = blockIdx.z;

    if (z == 3) {
        if (b) return;
#pragma unroll
        for (int t = 0; t < 8; ++t) {
            const int e  = threadIdx.x + 256 * t;   // 0..2047
            const int nl = e >> 5, k = e & 31;
            const int n  = n0 + nl;
            const int idx = Px[(size_t)n * K + k] * W + Py[(size_t)n * K + k];
            Idx[(size_t)n * K + (k & 7) * 4 + (k >> 3)] = (unsigned short)idx;
        }
        return;
    }

    __shared__ float tile[C][65];
    const float* src = (z == 0 ? S : (z == 1 ? R : Q)) + (size_t)b * C * N;
    __half2* d2 = (__half2*)((z == 0 ? St : (z == 1 ? Rt : Qt)) +
                             (size_t)b * N * C);
    {
        const int j = threadIdx.x & 63, c0 = threadIdx.x >> 6;
        const float* s = src + n0 + j;
#pragma unroll
        for (int r = 0; r < 16; ++r) {
            int c = c0 + r * 4;
            tile[c][j] = s[(size_t)c * N];  // coalesced 256B along n
        }
    }
    __syncthreads();
    {
        const int c2 = threadIdx.x & 31, j0 = threadIdx.x >> 5;
#pragma unroll
        for (int r = 0; r < 8; ++r) {
            int j = j0 + 8 * r;
            d2[(size_t)(n0 + j) * 32 + c2] =
                __floats2half2_rn(tile[2 * c2][j], tile[2 * c2 + 1][j]);
        }
    }
}

// ---------------------------------------------------------------------------
// Fused attention: phase 1 gathers K rows from St (4.19 MB/batch table,
// batch-pinned per XCD via bx&1), computes softmax, stashes weights in
// wave-private LDS (no barrier needed). Phase 2 gathers V rows from Rt and
// accumulates. Grid = 2048 = one co-resident pass, so blocks transition
// phases roughly together -> hot table stays ~4.19 MB/XCD per phase.
// block = 256 (4 waves; 1 wave = 8 pixels). LDS 12.5 KB.
// ---------------------------------------------------------------------------
__global__ __launch_bounds__(256, 6) void fepam_attn(
    const __half* __restrict__ Qt, const unsigned short* __restrict__ Idx,
    const __half* __restrict__ St, const __half* __restrict__ Rt,
    float* __restrict__ Out) {
    __shared__ __align__(16) float aw[32][32];  // 4 KB: weights, wave-private
    __shared__ __align__(16) float ot[32][66];  // 8.4 KB: output transpose

    const int tid  = threadIdx.x;
    const int lane = tid & 63;
    const int wave = tid >> 6;        // 0..3
    const int bx   = blockIdx.x;
    const int b    = bx & 1;          // XCD batch-parity swizzle
    const int n0t  = (bx >> 1) * 32;
    const int n0   = n0t + wave * 8;

    const int c_oct = lane & 7;
    const int k_loc = lane >> 3;

    const __half* Qtb = Qt + (size_t)b * N * C;
    const __half* Stb = St + (size_t)b * N * C;
    const __half* Rtb = Rt + (size_t)b * N * C;

    auto ldi = [&](int p) {
        return *(const ushort4*)(Idx + (size_t)(n0 + p) * K + k_loc * 4);
    };

    // ===================== phase 1: scores (verbatim R0) ===================
    {
        auto ldq = [&](int p) {
            return *(const float4*)(Qtb + (size_t)(n0 + p) * C + c_oct * 8);
        };
        auto ldk = [&](const ushort4& iv, int g) {
            return *(const float4*)(Stb + ((size_t)sel4(iv, g) << 6) +
                                    c_oct * 8);
        };

        ushort4 iv_c = ldi(0), iv_n = ldi(1);
        float4  q_c  = ldq(0), q_n  = ldq(1);
        float4  k_c[4];
#pragma unroll
        for (int g = 0; g < 4; ++g) k_c[g] = ldk(iv_c, g);

#pragma unroll
        for (int p = 0; p < 8; ++p) {
            // prefetch: keys for p+1, iv/q for p+2
            float4 k_n[4];
            if (p < 7) {
#pragma unroll
                for (int g = 0; g < 4; ++g) k_n[g] = ldk(iv_n, g);
            }
            ushort4 iv_2;
            float4  q_2;
            if (p < 6) { iv_2 = ldi(p + 2); q_2 = ldq(p + 2); }

            // ---- compute pixel p
            float s[4];
#pragma unroll
            for (int g = 0; g < 4; ++g) {
                const hf2* k2 = (const hf2*)&k_c[g];
                const hf2* q2 = (const hf2*)&q_c;
                float acc = 0.f;
#pragma unroll
                for (int u = 0; u < 4; ++u)
                    acc = __builtin_amdgcn_fdot2(k2[u], q2[u], acc, false);
                s[g] = acc;
            }
#pragma unroll
            for (int g = 0; g < 4; ++g) {  // reduce over c_oct: pure DPP
                s[g] += dppf<0xB1>(s[g]);
                s[g] += dppf<0x4E>(s[g]);
                s[g] += dppf<0x141>(s[g]);
            }
            float m = fmaxf(fmaxf(s[0], s[1]), fmaxf(s[2], s[3]));
            m = fmaxf(m, dppf<0x128>(m));
            m = fmaxf(m, __shfl_xor(m, 16));
            m = fmaxf(m, __shfl_xor(m, 32));
            float e0 = __expf(s[0] - m), e1 = __expf(s[1] - m);
            float e2 = __expf(s[2] - m), e3 = __expf(s[3] - m);
            float l = (e0 + e1) + (e2 + e3);
            l += dppf<0x128>(l);
            l += __shfl_xor(l, 16);
            l += __shfl_xor(l, 32);
            const float inv = 1.0f / l;

            if (c_oct == 0) {  // 8 lanes x 16B, wave-private LDS row
                *(float4*)&aw[wave * 8 + p][k_loc * 4] =
                    make_float4(e0 * inv, e1 * inv, e2 * inv, e3 * inv);
            }

            // ---- shift pipeline
#pragma unroll
            for (int g = 0; g < 4; ++g) k_c[g] = k_n[g];
            iv_c = iv_n; q_c = q_n;
            iv_n = iv_2; q_n = q_2;
        }
    }
    // No barrier: each wave reads only its own aw rows (LDS waits suffice).

    // ===================== phase 2: values (verbatim R0) ===================
    {
        const bool hi8  = (lane & 8)  != 0;
        const bool hi16 = (lane & 16) != 0;
        const bool hi32 = (lane & 32) != 0;

        auto ldv = [&](const ushort4& iv, int g) {
            return *(const float4*)(Rtb + ((size_t)sel4(iv, g) << 6) +
                                    c_oct * 8);
        };

        ushort4 i_c = ldi(0), i_n = ldi(1);
        float4  v_c[4];
#pragma unroll
        for (int g = 0; g < 4; ++g) v_c[g] = ldv(i_c, g);

#pragma unroll
        for (int p = 0; p < 8; ++p) {
            float4 v_n[4];
            if (p < 7) {
#pragma unroll
                for (int g = 0; g < 4; ++g) v_n[g] = ldv(i_n, g);
            }
            ushort4 i_2;
            if (p < 6) i_2 = ldi(p + 2);

            // ---- compute pixel p (weights from LDS stash)
            const float4 af = *(const float4*)&aw[wave * 8 + p][k_loc * 4];
            const float a[4] = {af.x, af.y, af.z, af.w};
            float acc[8] = {0, 0, 0, 0, 0, 0, 0, 0};
#pragma unroll
            for (int g = 0; g < 4; ++g) {
                const __half2* v2 = (const __half2*)&v_c[g];
#pragma unroll
                for (int u = 0; u < 4; ++u) {
                    const float2 vf = __half22float2(v2[u]);
                    acc[2 * u]     = fmaf(a[g], vf.x, acc[2 * u]);
                    acc[2 * u + 1] = fmaf(a[g], vf.y, acc[2 * u + 1]);
                }
            }

            // reduce acc[8] over k_loc (xor 8,16,32) with payload halving
            float r4[4];
#pragma unroll
            for (int i = 0; i < 4; ++i) {
                const float send = hi8 ? acc[i] : acc[4 + i];
                const float recv = dppf<0x128>(send);
                r4[i] = (hi8 ? acc[4 + i] : acc[i]) + recv;
            }
            float r2[2];
#pragma unroll
            for (int i = 0; i < 2; ++i) {
                const float send = hi16 ? r4[i] : r4[2 + i];
                const float recv = __shfl_xor(send, 16);
                r2[i] = (hi16 ? r4[2 + i] : r4[i]) + recv;
            }
            {
                const float send = hi32 ? r2[0] : r2[1];
                const float recv = __shfl_xor(send, 32);
                const float r1   = (hi32 ? r2[1] : r2[0]) + recv;
                const int c = c_oct * 8 + (hi8 ? 4 : 0) + (hi16 ? 2 : 0) +
                              (hi32 ? 1 : 0);
                ot[wave * 8 + p][c] = r1;
            }

            // ---- shift pipeline
#pragma unroll
            for (int g = 0; g < 4; ++g) v_c[g] = v_n[g];
            i_c = i_n;
            i_n = i_2;
        }
    }
    __syncthreads();

    // store: ot[j][c] -> Out[b][c][n0t+j] (two 128B segments per instr)
    {
        const int j = tid & 31, c0 = tid >> 5;
        float* od = Out + (size_t)b * C * N + n0t + j;
#pragma unroll
        for (int r = 0; r < 8; ++r) {
            int c = c0 + r * 8;
            od[(size_t)c * N] = ot[j][c];
        }
    }
}

// ---------------------------------------------------------------------------
extern "C" void kernel_launch(void* const* d_in, const int* in_sizes, int n_in,
                              void* d_out, int out_size, void* d_ws, size_t ws_size,
                              hipStream_t stream) {
    const float* Q  = (const float*)d_in[0];
    const float* S  = (const float*)d_in[1];
    const float* R  = (const float*)d_in[2];
    const int*   Px = (const int*)d_in[3];
    const int*   Py = (const int*)d_in[4];
    float* Out = (float*)d_out;

    // ws: St, Rt, Qt (8.39 MB each) + Idx (2.1 MB)
    __half* St = (__half*)d_ws;
    __half* Rt = St + (size_t)B * N * C;
    __half* Qt = Rt + (size_t)B * N * C;
    unsigned short* Idx = (unsigned short*)(Qt + (size_t)B * N * C);

    dim3 pgrid(N / 64, B, 4);
    fepam_prep<<<pgrid, 256, 0, stream>>>(Q, S, R, Px, Py, Qt, St, Rt, Idx);

    dim3 ggrid(N / 32 * B);
    fepam_attn<<<ggrid, 256, 0, stream>>>(Qt, Idx, St, Rt, Out);
}